// Round 8
// baseline (196.098 us; speedup 1.0000x reference)
//
#include <hip/hip_runtime.h>
#include <hip/hip_bf16.h>

typedef __attribute__((ext_vector_type(4))) float f32x4;
typedef __attribute__((ext_vector_type(8))) short bf16x8;

__device__ __forceinline__ void gload_lds16(const void* g, void* l) {
  __builtin_amdgcn_global_load_lds(
      (const __attribute__((address_space(1))) void*)g,
      (__attribute__((address_space(3))) void*)l, 16, 0, 0);
}

__device__ __forceinline__ unsigned short f2bf(float f) {
  union { float f; unsigned u; } x; x.f = f;
  unsigned r = x.u + 0x7fffu + ((x.u >> 16) & 1u);
  return (unsigned short)(r >> 16);
}

__device__ __forceinline__ float bf2f(unsigned short s) {
  union { unsigned u; float f; } x; x.u = (unsigned)s << 16;
  return x.f;
}

template<int N> __device__ __forceinline__ void vm_wait();
template<> __device__ __forceinline__ void vm_wait<0>() { asm volatile("s_waitcnt vmcnt(0)" ::: "memory"); }
template<> __device__ __forceinline__ void vm_wait<4>() { asm volatile("s_waitcnt vmcnt(4)" ::: "memory"); }
template<> __device__ __forceinline__ void vm_wait<6>() { asm volatile("s_waitcnt vmcnt(6)" ::: "memory"); }

#define BARRIER() asm volatile("s_barrier" ::: "memory")
#define SCHED0()  __builtin_amdgcn_sched_barrier(0)

// ---------------------------------------------------------------------------
// 256xBN 8-phase double-buffered GEMM body: C = f(alpha * A[M][K] @ Bt[N][K]^T)
// EPI: 0 = alpha only,
//      3 = exp(alpha*(acc + bias[bz*2048+col])) + atomic per-row sum into rs,
//      5 = acc * rcp(rs[row]) + bias[col].
// 512 threads, BK=64, T2 LDS swizzle, T4 counted vmcnt, T5 setprio.
// ---------------------------------------------------------------------------
template<int BN, int EPI, bool OUT_F32>
__device__ __forceinline__ void gemm_body(
    const unsigned short* __restrict__ A,
    const unsigned short* __restrict__ Bt,
    const float* __restrict__ bias,
    float* __restrict__ rs,
    void* __restrict__ Cout,
    int K, int lda, int ldb, int ldc, float alpha,
    long sA, long sB, long sC,
    int bx, int by, int bz, unsigned short* lds)
{
  constexpr int THREADS = 512;
  constexpr int WN = BN / 64;
  constexpr int WM = 8 / WN;
  constexpr int WTM = 256 / WM;
  constexpr int M_REP = WTM / 16;
  constexpr int MH = M_REP / 2;
  constexpr int ABUFE = 256 * 64;
  constexpr int BBUFE = BN * 64;
  constexpr int BBASE = 2 * ABUFE;
  constexpr int LOADS_A = 2;
  constexpr int LOADS_B = BN / 128;
  constexpr int VM_STEADY = 2 * LOADS_B + LOADS_A;  // 6 or 4

  const int tid = threadIdx.x, wave = tid >> 6, lane = tid & 63;
  const int wr = wave / WN, wc = wave % WN;
  const int fr = lane & 15, fq = lane >> 4, sw = fr & 7;

  A  += (size_t)bz * sA;
  Bt += (size_t)bz * sB;
  const int m0 = by * 256;
  const int n0 = bx * BN;
  const int NT = K >> 6;

  f32x4 acc[M_REP][4] = {};
  bf16x8 a[MH][2], b[4][2];

  auto stageA = [&](int t, int half) {
#pragma unroll
    for (int c = 0; c < LOADS_A; ++c) {
      const int s = c * THREADS + tid;
      const int rr = s >> 3;
      const int col = ((tid & 7) ^ (rr & 7)) * 8;
      gload_lds16(A + (size_t)(m0 + half * 128 + rr) * lda + t * 64 + col,
                  &lds[(t & 1) * ABUFE + half * (128 * 64) + s * 8]);
    }
  };
  auto stageB = [&](int t, int half) {
#pragma unroll
    for (int c = 0; c < LOADS_B; ++c) {
      const int s = c * THREADS + tid;
      const int rr = s >> 3;
      const int col = ((tid & 7) ^ (rr & 7)) * 8;
      gload_lds16(Bt + (size_t)(n0 + half * (BN / 2) + rr) * ldb + t * 64 + col,
                  &lds[BBASE + (t & 1) * BBUFE + half * ((BN / 2) * 64) + s * 8]);
    }
  };
  auto readA = [&](int buf, int mq) {
    const unsigned short* p = &lds[buf * ABUFE];
#pragma unroll
    for (int mm = 0; mm < MH; ++mm)
#pragma unroll
      for (int kk = 0; kk < 2; ++kk)
        a[mm][kk] = *(const bf16x8*)(p + (wr * WTM + mq * (WTM / 2) + mm * 16 + fr) * 64
                                       + ((kk * 4 + fq) ^ sw) * 8);
  };
  auto readB = [&](int buf, int nh) {
    const unsigned short* p = &lds[BBASE + buf * BBUFE];
#pragma unroll
    for (int nn = 0; nn < 2; ++nn)
#pragma unroll
      for (int kk = 0; kk < 2; ++kk)
        b[nh * 2 + nn][kk] = *(const bf16x8*)(p + (wc * 64 + (nh * 2 + nn) * 16 + fr) * 64
                                                + ((kk * 4 + fq) ^ sw) * 8);
  };
  auto mfmaQ = [&](int mq, int nh) {
    __builtin_amdgcn_s_setprio(1);
#pragma unroll
    for (int kk = 0; kk < 2; ++kk)
#pragma unroll
      for (int mm = 0; mm < MH; ++mm)
#pragma unroll
        for (int nn = 0; nn < 2; ++nn)
          acc[mq * MH + mm][nh * 2 + nn] = __builtin_amdgcn_mfma_f32_16x16x32_bf16(
              a[mm][kk], b[nh * 2 + nn][kk], acc[mq * MH + mm][nh * 2 + nn], 0, 0, 0);
    __builtin_amdgcn_s_setprio(0);
  };

  // prologue: tile0 fully, tile1 {B0,B1,A0}
  stageA(0, 0); stageA(0, 1); stageB(0, 0); stageB(0, 1);
  if (NT > 1) { stageB(1, 0); stageB(1, 1); stageA(1, 0); vm_wait<VM_STEADY>(); }
  else        { vm_wait<0>(); }
  BARRIER();

  for (int t = 0; t < NT; ++t) {
    const int buf = t & 1;
    // ph1
    readA(buf, 0); readB(buf, 0);
    BARRIER(); SCHED0();
    mfmaQ(0, 0);
    SCHED0();
    BARRIER();
    // ph2
    readB(buf, 1);
    if (t + 1 < NT) stageA(t + 1, 1);
    BARRIER(); SCHED0();
    mfmaQ(0, 1);
    SCHED0();
    BARRIER();
    // ph3
    readA(buf, 1);
    if (t + 2 < NT) stageB(t + 2, 0);
    BARRIER(); SCHED0();
    mfmaQ(1, 0);
    SCHED0();
    BARRIER();
    // ph4
    if (t + 2 < NT) { stageB(t + 2, 1); stageA(t + 2, 0); vm_wait<VM_STEADY>(); }
    else            { vm_wait<0>(); }
    BARRIER(); SCHED0();
    mfmaQ(1, 1);
    SCHED0();
    BARRIER();
  }

  // epilogue (nn innermost for L2 write combining)
  float bvc[4];
  if (EPI == 5) {
#pragma unroll
    for (int nn = 0; nn < 4; ++nn) bvc[nn] = bias[n0 + wc * 64 + nn * 16 + fr];
  }
  if (EPI == 3) {
#pragma unroll
    for (int nn = 0; nn < 4; ++nn)
      bvc[nn] = bias[(size_t)bz * 2048 + n0 + wc * 64 + nn * 16 + fr];
  }
#pragma unroll
  for (int mm = 0; mm < M_REP; ++mm) {
    const int rbase = m0 + wr * WTM + mm * 16 + fq * 4;
#pragma unroll
    for (int j = 0; j < 4; ++j) {
      const int row = rbase + j;
      float rsc = 1.f;
      if (EPI == 5) rsc = __builtin_amdgcn_rcpf(rs[(size_t)bz * 2048 + row]);
      float part = 0.f;
#pragma unroll
      for (int nn = 0; nn < 4; ++nn) {
        const int col = n0 + wc * 64 + nn * 16 + fr;
        float v = acc[mm][nn][j];
        if      (EPI == 3) { v = __expf((v + bvc[nn]) * alpha); part += v; }
        else if (EPI == 5) v = v * rsc + bvc[nn];
        else               v = v * alpha;
        const size_t off = (size_t)bz * sC + (size_t)row * ldc + col;
        if (OUT_F32) ((float*)Cout)[off] = v;
        else         ((unsigned short*)Cout)[off] = f2bf(v);
      }
      if (EPI == 3) {
        part += __shfl_xor(part, 1); part += __shfl_xor(part, 2);
        part += __shfl_xor(part, 4); part += __shfl_xor(part, 8);
        if (fr == 0) atomicAdd(rs + (size_t)bz * 2048 + row, part);
      }
    }
  }
}

// bijective XCD-chunked swizzle over nwg blocks; returns remapped linear id
__device__ __forceinline__ int xcd_swz(int lid, int nwg) {
  const int q = nwg >> 3, r = nwg & 7;
  const int xcd = lid & 7, idx = lid >> 3;
  return (xcd < r ? xcd * (q + 1) : r * (q + 1) + (xcd - r) * q) + idx;
}

// ---------------------------------------------------------------------------
template<int BN, int EPI, bool OUT_F32>
__global__ __launch_bounds__(512, 2)
void gemm256(const unsigned short* __restrict__ A,
             const unsigned short* __restrict__ Bt,
             const float* __restrict__ bias,
             float* __restrict__ rs,
             void* __restrict__ Cout,
             int K, int lda, int ldb, int ldc, float alpha,
             long sA, long sB, long sC)
{
  __shared__ __attribute__((aligned(16))) unsigned short lds[2 * 256 * 64 + 2 * BN * 64];
  const int gx = gridDim.x, gy = gridDim.y;
  const int lid = blockIdx.x + gx * (blockIdx.y + gy * blockIdx.z);
  const int nl = xcd_swz(lid, gx * gy * gridDim.z);
  const int bx = nl % gx, by = (nl / gx) % gy, bz = nl / (gx * gy);
  gemm_body<BN, EPI, OUT_F32>(A, Bt, bias, rs, Cout, K, lda, ldb, ldc, alpha,
                              sA, sB, sC, bx, by, bz, lds);
}

// dual launch: blocks [0,256) = GEMM0 (grid 8x32x1), [256,512) = GEMM1 (16x4x4)
__global__ __launch_bounds__(512, 2)
void gemm256_dual(const unsigned short* __restrict__ A0, const unsigned short* __restrict__ B0,
                  void* __restrict__ C0,
                  const unsigned short* __restrict__ A1, const unsigned short* __restrict__ B1,
                  void* __restrict__ C1,
                  long sA1, long sB1, long sC1)
{
  __shared__ __attribute__((aligned(16))) unsigned short lds[2 * 256 * 64 + 2 * 128 * 64];
  const int f = blockIdx.x;
  if (f < 256) {
    const int nl = xcd_swz(f, 256);
    const int bx = nl & 7, by = nl >> 3;   // gx=8, gy=32
    gemm_body<128, 0, false>(A0, B0, nullptr, nullptr, C0,
                             1024, 1024, 1024, 1024, 1.f, 0, 0, 0, bx, by, 0, lds);
  } else {
    const int nl = xcd_swz(f - 256, 256);
    const int bx = nl & 15, by = (nl >> 4) & 3, bz = nl >> 6;  // gx=16, gy=4, gz=4
    gemm_body<128, 0, false>(A1, B1, nullptr, nullptr, C1,
                             1024, 1024, 1024, 2048, 1.f, sA1, sB1, sC1, bx, by, bz, lds);
  }
}

// ---------------------------------------------------------------------------
// x fp32 -> bf16, 2048 elements per block
__global__ __launch_bounds__(256)
void convert_kernel(const float* __restrict__ x, unsigned short* __restrict__ xb)
{
  const int idx = (blockIdx.x * 256 + threadIdx.x) * 8;
  const float4 a = *(const float4*)(x + idx);
  const float4 b = *(const float4*)(x + idx + 4);
  unsigned u0 = (unsigned)f2bf(a.x) | ((unsigned)f2bf(a.y) << 16);
  unsigned u1 = (unsigned)f2bf(a.z) | ((unsigned)f2bf(a.w) << 16);
  unsigned u2 = (unsigned)f2bf(b.x) | ((unsigned)f2bf(b.y) << 16);
  unsigned u3 = (unsigned)f2bf(b.z) | ((unsigned)f2bf(b.w) << 16);
  uint4 o; o.x = u0; o.y = u1; o.z = u2; o.w = u3;
  *(uint4*)(xb + idx) = o;
}

// ---------------------------------------------------------------------------
// weights_prep, flat grid 2064 blocks x 256 threads:
//  [0,1536)    : convert W1/W2/W3 fp32->bf16 (512 blocks each)
//  [1536,1792) : transpose W4 -> W4t bf16 [e][j]
//  [1792,1808) : bfv[e] = b4[e] + sum_j b3[j]*W4[j][e]   (fp32 read)
//  [1808,2064) : w21[f] = sum_n W2[f][n]*b1[n]
// ---------------------------------------------------------------------------
__global__ __launch_bounds__(256)
void weights_prep(const float* __restrict__ W1, const float* __restrict__ W2,
                  const float* __restrict__ W3, const float* __restrict__ W4,
                  const float* __restrict__ b1, const float* __restrict__ b3,
                  const float* __restrict__ b4,
                  unsigned short* __restrict__ W1b, unsigned short* __restrict__ W2b,
                  unsigned short* __restrict__ W3b, unsigned short* __restrict__ W4t,
                  float* __restrict__ w21, float* __restrict__ bfv)
{
  __shared__ float t[64][65];
  const int f = blockIdx.x, tid = threadIdx.x;
  if (f < 1536) {
    const int which = f >> 9, blk = f & 511;
    const float* src = (which == 0) ? W1 : (which == 1) ? W2 : W3;
    unsigned short* dst = (which == 0) ? W1b : (which == 1) ? W2b : W3b;
    const int idx = (blk * 256 + tid) * 8;
    const float4 p = *(const float4*)(src + idx);
    const float4 q = *(const float4*)(src + idx + 4);
    unsigned u0 = (unsigned)f2bf(p.x) | ((unsigned)f2bf(p.y) << 16);
    unsigned u1 = (unsigned)f2bf(p.z) | ((unsigned)f2bf(p.w) << 16);
    unsigned u2 = (unsigned)f2bf(q.x) | ((unsigned)f2bf(q.y) << 16);
    unsigned u3 = (unsigned)f2bf(q.z) | ((unsigned)f2bf(q.w) << 16);
    uint4 o; o.x = u0; o.y = u1; o.z = u2; o.w = u3;
    *(uint4*)(dst + idx) = o;
  } else if (f < 1792) {
    const int tb = f - 1536;
    const int k0 = (tb >> 4) * 64, n0 = (tb & 15) * 64;
    const int tx = tid & 63, ty = tid >> 6;
#pragma unroll
    for (int r = ty; r < 64; r += 4)
      t[r][tx] = W4[(size_t)(k0 + r) * 1024 + n0 + tx];
    __syncthreads();
#pragma unroll
    for (int r = ty; r < 64; r += 4)
      W4t[(size_t)(n0 + r) * 1024 + k0 + tx] = f2bf(t[tx][r]);
  } else if (f < 1808) {
    const int e0 = (f - 1792) * 64;
    const int tx = tid & 63, ty = tid >> 6;
    float acc = 0.f;
    for (int j = ty; j < 1024; j += 4)
      acc += b3[j] * W4[(size_t)j * 1024 + e0 + tx];
    t[ty][tx] = acc;
    __syncthreads();
    if (ty == 0)
      bfv[e0 + tx] = t[0][tx] + t[1][tx] + t[2][tx] + t[3][tx] + b4[e0 + tx];
  } else {
    const int e = (f - 1808) * 4 + (tid >> 6);
    const int lane = tid & 63;
    float acc = 0.f;
#pragma unroll 4
    for (int i = 0; i < 16; ++i) {
      const int n = i * 64 + lane;
      acc += W2[(size_t)e * 1024 + n] * b1[n];
    }
#pragma unroll
    for (int o = 32; o; o >>= 1) acc += __shfl_xor(acc, o);
    if (lane == 0) w21[e] = acc;
  }
}

// ---------------------------------------------------------------------------
// prep2, flat grid 640 blocks x 256 threads:
//  [0,128)   : Mtb = W2b @ W1b^T (z=0) / W34tb = W4t @ W3b^T (z=1), 128^2 tile
//  [128,640) : v[i] = xb[i].w21 (16 rows per block); blocks 128..131 also zero rsum
// ---------------------------------------------------------------------------
__global__ __launch_bounds__(256, 2)
void prep2(const unsigned short* __restrict__ W2b, const unsigned short* __restrict__ W1b,
           const unsigned short* __restrict__ W4t, const unsigned short* __restrict__ W3b,
           unsigned short* __restrict__ Mtb, unsigned short* __restrict__ W34tb,
           const unsigned short* __restrict__ xb, const float* __restrict__ w21,
           float* __restrict__ vvec, float* __restrict__ rsum)
{
  __shared__ __attribute__((aligned(16))) unsigned short As[128 * 32];
  __shared__ __attribute__((aligned(16))) unsigned short Bs[128 * 32];
  const int f = blockIdx.x, tid = threadIdx.x;
  if (f < 128) {
    const int which = f >> 6, blk = f & 63;
    const unsigned short* A  = which ? W4t : W2b;
    const unsigned short* Bt = which ? W3b : W1b;
    unsigned short* C = which ? W34tb : Mtb;
    const int m0 = (blk >> 3) * 128, n0 = (blk & 7) * 128;
    const int wave = tid >> 6, lane = tid & 63;
    f32x4 acc[4][4] = {};
    const int wr = wave >> 1, wc = wave & 1;
    const int fr = lane & 15, fq = lane >> 4;
    const int si0 = wave * 2, sr = lane >> 2, sce = (lane & 3) * 8;
    for (int k0 = 0; k0 < 1024; k0 += 32) {
#pragma unroll
      for (int c = 0; c < 2; ++c) {
        const int i = si0 + c, rr = i * 16 + sr;
        gload_lds16(A  + (size_t)(m0 + rr) * 1024 + k0 + sce, As + i * 512 + lane * 8);
        gload_lds16(Bt + (size_t)(n0 + rr) * 1024 + k0 + sce, Bs + i * 512 + lane * 8);
      }
      __syncthreads();
      bf16x8 af[4], bg[4];
#pragma unroll
      for (int m = 0; m < 4; ++m)
        af[m] = *(const bf16x8*)(As + (wr * 64 + m * 16 + fr) * 32 + fq * 8);
#pragma unroll
      for (int n = 0; n < 4; ++n)
        bg[n] = *(const bf16x8*)(Bs + (wc * 64 + n * 16 + fr) * 32 + fq * 8);
#pragma unroll
      for (int m = 0; m < 4; ++m)
#pragma unroll
        for (int n = 0; n < 4; ++n)
          acc[m][n] = __builtin_amdgcn_mfma_f32_16x16x32_bf16(af[m], bg[n], acc[m][n], 0, 0, 0);
      __syncthreads();
    }
#pragma unroll
    for (int m = 0; m < 4; ++m) {
      const int rbase = m0 + wr * 64 + m * 16 + fq * 4;
#pragma unroll
      for (int j = 0; j < 4; ++j)
#pragma unroll
        for (int n = 0; n < 4; ++n)
          C[(size_t)(rbase + j) * 1024 + (n0 + wc * 64 + n * 16 + fr)] = f2bf(acc[m][n][j]);
    }
  } else {
    const int f2 = f - 128;
    if (f2 < 4) {
      uint4 z = {0, 0, 0, 0};
      float* p = rsum + f2 * 2048 + tid * 8;
      *(uint4*)p = z; *(uint4*)(p + 4) = z;
    }
    const int wave = tid >> 6, lane = tid & 63;
#pragma unroll 4
    for (int rr = 0; rr < 4; ++rr) {
      const int i = f2 * 16 + wave * 4 + rr;
      const unsigned short* row = xb + (size_t)i * 1024;
      float acc = 0.f;
#pragma unroll 2
      for (int it = 0; it < 2; ++it) {
        const int k0 = (it * 64 + lane) * 8;
        bf16x8 pk = *(const bf16x8*)(row + k0);
#pragma unroll
        for (int j = 0; j < 8; ++j)
          acc += bf2f(((const unsigned short*)&pk)[j]) * w21[k0 + j];
      }
#pragma unroll
      for (int o = 32; o; o >>= 1) acc += __shfl_xor(acc, o);
      if (lane == 0) vvec[i] = acc;
    }
  }
}

// ---------------------------------------------------------------------------
extern "C" void kernel_launch(void* const* d_in, const int* in_sizes, int n_in,
                              void* d_out, int out_size, void* d_ws, size_t ws_size,
                              hipStream_t stream)
{
  const float* x  = (const float*)d_in[0];
  const float* W1 = (const float*)d_in[1];
  const float* b1 = (const float*)d_in[2];
  const float* W2 = (const float*)d_in[3];
  // b2 unused: cancels in softmax (row-constant terms)
  const float* W3 = (const float*)d_in[5];
  const float* b3 = (const float*)d_in[6];
  const float* W4 = (const float*)d_in[7];
  const float* b4 = (const float*)d_in[8];

  char* ws = (char*)d_ws;
  const size_t MB = 1024 * 1024;
  unsigned short* xb    = (unsigned short*)(ws);            // 16MB
  unsigned short* W4t   = (unsigned short*)(ws + 16 * MB);  // 2MB
  unsigned short* W2b   = (unsigned short*)(ws + 18 * MB);  // 2MB
  unsigned short* W1b   = (unsigned short*)(ws + 20 * MB);  // 2MB
  unsigned short* W3b   = (unsigned short*)(ws + 22 * MB);  // 2MB
  unsigned short* G     = (unsigned short*)(ws + 24 * MB);  // 16MB: x @ M
  unsigned short* Mtb   = (unsigned short*)(ws + 40 * MB);  // 2MB
  unsigned short* W34tb = (unsigned short*)(ws + 42 * MB);  // 2MB
  float*          rsum  = (float*)(ws + 44 * MB);           // 32KB
  float*          bfv   = (float*)(ws + 45 * MB);           // 4KB
  float*          w21   = (float*)(ws + 45 * MB + 8192);    // 4KB
  float*          vvec  = (float*)(ws + 45 * MB + 16384);   // 32KB
  unsigned short* Vt    = (unsigned short*)(ws + 56 * MB);  // 16MB
  unsigned short* S     = (unsigned short*)(ws + 72 * MB);  // 32MB exp values

  // 1. x -> bf16
  convert_kernel<<<4096, 256, 0, stream>>>(x, xb);

  // 2. all weight prep (converts, W4 transpose, w21, bfv)
  weights_prep<<<2064, 256, 0, stream>>>(W1, W2, W3, W4, b1, b3, b4,
                                         W1b, W2b, W3b, W4t, w21, bfv);

  // 3. Mtb/W34tb GEMMs + v-vector + rsum zero
  prep2<<<640, 256, 0, stream>>>(W2b, W1b, W4t, W3b, Mtb, W34tb, xb, w21, vvec, rsum);

  // 4. G = xb @ Mtb^T  [8192][1024]  ||  Vt[z] = W34tb @ xb[z]^T  [4][1024][2048]
  gemm256_dual<<<512, 512, 0, stream>>>(xb, Mtb, G, W34tb, xb, Vt,
                                        0, 2048L * 1024, 1024L * 2048);

  // 5. S[z] = exp((G[z] @ xb[z]^T + v[col]) / 32), rowsum -> rsum
  gemm256<256, 3, false><<<dim3(8, 8, 4), 512, 0, stream>>>(
      G, xb, vvec, rsum, S, 1024, 1024, 1024, 2048, 0.03125f,
      2048L * 1024, 2048L * 1024, 2048L * 2048);

  // 6. out[z] = (S[z] @ V'[z]) * rcp(rsum[row]) + bfv[col]  (fp32)
  gemm256<128, 5, true><<<dim3(8, 8, 4), 512, 0, stream>>>(
      S, Vt, bfv, rsum, d_out, 2048, 2048, 2048, 1024, 1.f,
      2048L * 2048, 1024L * 2048, 2048L * 1024);
}

// Round 9
// 169.351 us; speedup vs baseline: 1.1579x; 1.1579x over previous
//
#include <hip/hip_runtime.h>
#include <hip/hip_bf16.h>

typedef __attribute__((ext_vector_type(4))) float f32x4;
typedef __attribute__((ext_vector_type(8))) short bf16x8;

__device__ __forceinline__ void gload_lds16(const void* g, void* l) {
  __builtin_amdgcn_global_load_lds(
      (const __attribute__((address_space(1))) void*)g,
      (__attribute__((address_space(3))) void*)l, 16, 0, 0);
}

__device__ __forceinline__ unsigned short f2bf(float f) {
  union { float f; unsigned u; } x; x.f = f;
  unsigned r = x.u + 0x7fffu + ((x.u >> 16) & 1u);
  return (unsigned short)(r >> 16);
}

__device__ __forceinline__ float bf2f(unsigned short s) {
  union { unsigned u; float f; } x; x.u = (unsigned)s << 16;
  return x.f;
}

template<int N> __device__ __forceinline__ void vm_wait();
template<> __device__ __forceinline__ void vm_wait<0>() { asm volatile("s_waitcnt vmcnt(0)" ::: "memory"); }
template<> __device__ __forceinline__ void vm_wait<4>() { asm volatile("s_waitcnt vmcnt(4)" ::: "memory"); }
template<> __device__ __forceinline__ void vm_wait<6>() { asm volatile("s_waitcnt vmcnt(6)" ::: "memory"); }

#define BARRIER() asm volatile("s_barrier" ::: "memory")
#define SCHED0()  __builtin_amdgcn_sched_barrier(0)

// ---------------------------------------------------------------------------
// 256xBN 8-phase double-buffered GEMM: C = f(alpha * A[M][K] @ Bt[N][K]^T)
// EPI: 0 = alpha only,
//      3 = exp(alpha*(acc + bias[bz*2048+col])) + atomic per-row sum into rs,
//      5 = acc * rcp(rs[row]) + bias[col].
// 512 threads, BK=64, T1 XCD swizzle, T2 LDS swizzle, T4 counted vmcnt, T5.
// ---------------------------------------------------------------------------
template<int BN, int EPI, bool OUT_F32>
__global__ __launch_bounds__(512, 2)
void gemm256(const unsigned short* __restrict__ A,
             const unsigned short* __restrict__ Bt,
             const float* __restrict__ bias,
             float* __restrict__ rs,
             void* __restrict__ Cout,
             int K, int lda, int ldb, int ldc, float alpha,
             long sA, long sB, long sC)
{
  constexpr int THREADS = 512;
  constexpr int WN = BN / 64;          // waves along N (4 or 2)
  constexpr int WM = 8 / WN;           // waves along M (2 or 4)
  constexpr int WTM = 256 / WM;        // wave M extent (128 or 64)
  constexpr int M_REP = WTM / 16;      // 8 or 4
  constexpr int MH = M_REP / 2;        // 4 or 2
  constexpr int ABUFE = 256 * 64;
  constexpr int BBUFE = BN * 64;
  constexpr int BBASE = 2 * ABUFE;
  constexpr int LOADS_A = 2;
  constexpr int LOADS_B = BN / 128;
  constexpr int VM_STEADY = 2 * LOADS_B + LOADS_A;  // 6 or 4

  __shared__ __attribute__((aligned(16))) unsigned short lds[BBASE + 2 * BBUFE];

  // bijective XCD-chunked swizzle
  const int gx = gridDim.x, gy = gridDim.y;
  const int lid = blockIdx.x + gx * (blockIdx.y + gy * blockIdx.z);
  const int nwg = gx * gy * gridDim.z;
  const int q = nwg >> 3, r = nwg & 7;
  const int xcd = lid & 7, idx = lid >> 3;
  const int nl = (xcd < r ? xcd * (q + 1) : r * (q + 1) + (xcd - r) * q) + idx;
  const int bx = nl % gx, by = (nl / gx) % gy, bz = nl / (gx * gy);

  const int tid = threadIdx.x, wave = tid >> 6, lane = tid & 63;
  const int wr = wave / WN, wc = wave % WN;
  const int fr = lane & 15, fq = lane >> 4, sw = fr & 7;

  A  += (size_t)bz * sA;
  Bt += (size_t)bz * sB;
  const int m0 = by * 256;
  const int n0 = bx * BN;
  const int NT = K >> 6;

  f32x4 acc[M_REP][4] = {};
  bf16x8 a[MH][2], b[4][2];

  auto stageA = [&](int t, int half) {
#pragma unroll
    for (int c = 0; c < LOADS_A; ++c) {
      const int s = c * THREADS + tid;
      const int rr = s >> 3;
      const int col = ((tid & 7) ^ (rr & 7)) * 8;
      gload_lds16(A + (size_t)(m0 + half * 128 + rr) * lda + t * 64 + col,
                  &lds[(t & 1) * ABUFE + half * (128 * 64) + s * 8]);
    }
  };
  auto stageB = [&](int t, int half) {
#pragma unroll
    for (int c = 0; c < LOADS_B; ++c) {
      const int s = c * THREADS + tid;
      const int rr = s >> 3;
      const int col = ((tid & 7) ^ (rr & 7)) * 8;
      gload_lds16(Bt + (size_t)(n0 + half * (BN / 2) + rr) * ldb + t * 64 + col,
                  &lds[BBASE + (t & 1) * BBUFE + half * ((BN / 2) * 64) + s * 8]);
    }
  };
  auto readA = [&](int buf, int mq) {
    const unsigned short* p = &lds[buf * ABUFE];
#pragma unroll
    for (int mm = 0; mm < MH; ++mm)
#pragma unroll
      for (int kk = 0; kk < 2; ++kk)
        a[mm][kk] = *(const bf16x8*)(p + (wr * WTM + mq * (WTM / 2) + mm * 16 + fr) * 64
                                       + ((kk * 4 + fq) ^ sw) * 8);
  };
  auto readB = [&](int buf, int nh) {
    const unsigned short* p = &lds[BBASE + buf * BBUFE];
#pragma unroll
    for (int nn = 0; nn < 2; ++nn)
#pragma unroll
      for (int kk = 0; kk < 2; ++kk)
        b[nh * 2 + nn][kk] = *(const bf16x8*)(p + (wc * 64 + (nh * 2 + nn) * 16 + fr) * 64
                                                + ((kk * 4 + fq) ^ sw) * 8);
  };
  auto mfmaQ = [&](int mq, int nh) {
    __builtin_amdgcn_s_setprio(1);
#pragma unroll
    for (int kk = 0; kk < 2; ++kk)
#pragma unroll
      for (int mm = 0; mm < MH; ++mm)
#pragma unroll
        for (int nn = 0; nn < 2; ++nn)
          acc[mq * MH + mm][nh * 2 + nn] = __builtin_amdgcn_mfma_f32_16x16x32_bf16(
              a[mm][kk], b[nh * 2 + nn][kk], acc[mq * MH + mm][nh * 2 + nn], 0, 0, 0);
    __builtin_amdgcn_s_setprio(0);
  };

  // prologue: tile0 fully, tile1 {B0,B1,A0}
  stageA(0, 0); stageA(0, 1); stageB(0, 0); stageB(0, 1);
  if (NT > 1) { stageB(1, 0); stageB(1, 1); stageA(1, 0); vm_wait<VM_STEADY>(); }
  else        { vm_wait<0>(); }
  BARRIER();

  for (int t = 0; t < NT; ++t) {
    const int buf = t & 1;
    // ph1
    readA(buf, 0); readB(buf, 0);
    BARRIER(); SCHED0();
    mfmaQ(0, 0);
    SCHED0();
    BARRIER();
    // ph2
    readB(buf, 1);
    if (t + 1 < NT) stageA(t + 1, 1);
    BARRIER(); SCHED0();
    mfmaQ(0, 1);
    SCHED0();
    BARRIER();
    // ph3
    readA(buf, 1);
    if (t + 2 < NT) stageB(t + 2, 0);
    BARRIER(); SCHED0();
    mfmaQ(1, 0);
    SCHED0();
    BARRIER();
    // ph4
    if (t + 2 < NT) { stageB(t + 2, 1); stageA(t + 2, 0); vm_wait<VM_STEADY>(); }
    else            { vm_wait<0>(); }
    BARRIER(); SCHED0();
    mfmaQ(1, 1);
    SCHED0();
    BARRIER();
  }

  // epilogue (nn innermost for L2 write combining)
  float bvc[4];
  if (EPI == 5) {
#pragma unroll
    for (int nn = 0; nn < 4; ++nn) bvc[nn] = bias[n0 + wc * 64 + nn * 16 + fr];
  }
  if (EPI == 3) {
#pragma unroll
    for (int nn = 0; nn < 4; ++nn)
      bvc[nn] = bias[(size_t)bz * 2048 + n0 + wc * 64 + nn * 16 + fr];
  }
#pragma unroll
  for (int mm = 0; mm < M_REP; ++mm) {
    const int rbase = m0 + wr * WTM + mm * 16 + fq * 4;
#pragma unroll
    for (int j = 0; j < 4; ++j) {
      const int row = rbase + j;
      float rsc = 1.f;
      if (EPI == 5) rsc = __builtin_amdgcn_rcpf(rs[(size_t)bz * 2048 + row]);
      float part = 0.f;
#pragma unroll
      for (int nn = 0; nn < 4; ++nn) {
        const int col = n0 + wc * 64 + nn * 16 + fr;
        float v = acc[mm][nn][j];
        if      (EPI == 3) { v = __expf((v + bvc[nn]) * alpha); part += v; }
        else if (EPI == 5) v = v * rsc + bvc[nn];
        else               v = v * alpha;
        const size_t off = (size_t)bz * sC + (size_t)row * ldc + col;
        if (OUT_F32) ((float*)Cout)[off] = v;
        else         ((unsigned short*)Cout)[off] = f2bf(v);
      }
      if (EPI == 3) {
        part += __shfl_xor(part, 1); part += __shfl_xor(part, 2);
        part += __shfl_xor(part, 4); part += __shfl_xor(part, 8);
        if (fr == 0) atomicAdd(rs + (size_t)bz * 2048 + row, part);
      }
    }
  }
}

// ---------------------------------------------------------------------------
// bigprep, flat grid 6144 blocks x 256 threads (all round-7-proven patterns):
//  [0,4096)    : x fp32 -> bf16 (2048 elems/block)
//  [4096,5632) : convert W1/W2/W3 fp32->bf16 (512 blocks each)
//  [5632,5888) : transpose W4 -> W4t bf16 [e][j]
//  [5888,6144) : w21[f] = sum_n W2[f][n]*b1[n]  (fp32 reads, indep of converts)
// ---------------------------------------------------------------------------
__global__ __launch_bounds__(256)
void bigprep(const float* __restrict__ x,
             const float* __restrict__ W1, const float* __restrict__ W2,
             const float* __restrict__ W3, const float* __restrict__ W4,
             const float* __restrict__ b1,
             unsigned short* __restrict__ xb,
             unsigned short* __restrict__ W1b, unsigned short* __restrict__ W2b,
             unsigned short* __restrict__ W3b, unsigned short* __restrict__ W4t,
             float* __restrict__ w21)
{
  __shared__ float t[64][65];
  const int f = blockIdx.x, tid = threadIdx.x;
  if (f < 5632) {
    const float* src;
    unsigned short* dst;
    int blk;
    if (f < 4096) { src = x; dst = xb; blk = f; }
    else {
      const int which = (f - 4096) >> 9;
      blk = (f - 4096) & 511;
      src = (which == 0) ? W1 : (which == 1) ? W2 : W3;
      dst = (which == 0) ? W1b : (which == 1) ? W2b : W3b;
    }
    const int idx = (blk * 256 + tid) * 8;
    const float4 p = *(const float4*)(src + idx);
    const float4 q = *(const float4*)(src + idx + 4);
    unsigned u0 = (unsigned)f2bf(p.x) | ((unsigned)f2bf(p.y) << 16);
    unsigned u1 = (unsigned)f2bf(p.z) | ((unsigned)f2bf(p.w) << 16);
    unsigned u2 = (unsigned)f2bf(q.x) | ((unsigned)f2bf(q.y) << 16);
    unsigned u3 = (unsigned)f2bf(q.z) | ((unsigned)f2bf(q.w) << 16);
    uint4 o; o.x = u0; o.y = u1; o.z = u2; o.w = u3;
    *(uint4*)(dst + idx) = o;
  } else if (f < 5888) {
    const int tb = f - 5632;
    const int k0 = (tb >> 4) * 64, n0 = (tb & 15) * 64;
    const int tx = tid & 63, ty = tid >> 6;
#pragma unroll
    for (int r = ty; r < 64; r += 4)
      t[r][tx] = W4[(size_t)(k0 + r) * 1024 + n0 + tx];
    __syncthreads();
#pragma unroll
    for (int r = ty; r < 64; r += 4)
      W4t[(size_t)(n0 + r) * 1024 + k0 + tx] = f2bf(t[tx][r]);
  } else {
    const int e = (f - 5888) * 4 + (tid >> 6);
    const int lane = tid & 63;
    float acc = 0.f;
#pragma unroll 4
    for (int i = 0; i < 16; ++i) {
      const int n = i * 64 + lane;
      acc += W2[(size_t)e * 1024 + n] * b1[n];
    }
#pragma unroll
    for (int o = 32; o; o >>= 1) acc += __shfl_xor(acc, o);
    if (lane == 0) w21[e] = acc;
  }
}

// ---------------------------------------------------------------------------
// prep2, flat grid 896 blocks x 256 threads:
//  [0,128)   : Mtb = W2b @ W1b^T (z=0) / W34tb = W4t @ W3b^T (z=1), 128^2 tile
//  [128,640) : v[i] = xb[i].w21 (16 rows/block); blocks 128..131 also zero rsum
//  [640,896) : bfv[e] = b4[e] + sum_j b3[j]*W4t[e][j]  (coalesced bf16 rows)
// ---------------------------------------------------------------------------
__global__ __launch_bounds__(256, 2)
void prep2(const unsigned short* __restrict__ W2b, const unsigned short* __restrict__ W1b,
           const unsigned short* __restrict__ W4t, const unsigned short* __restrict__ W3b,
           unsigned short* __restrict__ Mtb, unsigned short* __restrict__ W34tb,
           const unsigned short* __restrict__ xb, const float* __restrict__ w21,
           const float* __restrict__ b3, const float* __restrict__ b4,
           float* __restrict__ vvec, float* __restrict__ rsum, float* __restrict__ bfv)
{
  __shared__ __attribute__((aligned(16))) unsigned short As[128 * 32];
  __shared__ __attribute__((aligned(16))) unsigned short Bs[128 * 32];
  const int f = blockIdx.x, tid = threadIdx.x;
  if (f < 128) {
    const int which = f >> 6, blk = f & 63;
    const unsigned short* A  = which ? W4t : W2b;
    const unsigned short* Bt = which ? W3b : W1b;
    unsigned short* C = which ? W34tb : Mtb;
    const int m0 = (blk >> 3) * 128, n0 = (blk & 7) * 128;
    const int wave = tid >> 6, lane = tid & 63;
    f32x4 acc[4][4] = {};
    const int wr = wave >> 1, wc = wave & 1;
    const int fr = lane & 15, fq = lane >> 4;
    const int si0 = wave * 2, sr = lane >> 2, sce = (lane & 3) * 8;
    for (int k0 = 0; k0 < 1024; k0 += 32) {
#pragma unroll
      for (int c = 0; c < 2; ++c) {
        const int i = si0 + c, rr = i * 16 + sr;
        gload_lds16(A  + (size_t)(m0 + rr) * 1024 + k0 + sce, As + i * 512 + lane * 8);
        gload_lds16(Bt + (size_t)(n0 + rr) * 1024 + k0 + sce, Bs + i * 512 + lane * 8);
      }
      __syncthreads();
      bf16x8 af[4], bg[4];
#pragma unroll
      for (int m = 0; m < 4; ++m)
        af[m] = *(const bf16x8*)(As + (wr * 64 + m * 16 + fr) * 32 + fq * 8);
#pragma unroll
      for (int n = 0; n < 4; ++n)
        bg[n] = *(const bf16x8*)(Bs + (wc * 64 + n * 16 + fr) * 32 + fq * 8);
#pragma unroll
      for (int m = 0; m < 4; ++m)
#pragma unroll
        for (int n = 0; n < 4; ++n)
          acc[m][n] = __builtin_amdgcn_mfma_f32_16x16x32_bf16(af[m], bg[n], acc[m][n], 0, 0, 0);
      __syncthreads();
    }
#pragma unroll
    for (int m = 0; m < 4; ++m) {
      const int rbase = m0 + wr * 64 + m * 16 + fq * 4;
#pragma unroll
      for (int j = 0; j < 4; ++j)
#pragma unroll
        for (int n = 0; n < 4; ++n)
          C[(size_t)(rbase + j) * 1024 + (n0 + wc * 64 + n * 16 + fr)] = f2bf(acc[m][n][j]);
    }
  } else if (f < 640) {
    const int f2 = f - 128;
    if (f2 < 4) {
      uint4 z = {0, 0, 0, 0};
      float* p = rsum + f2 * 2048 + tid * 8;
      *(uint4*)p = z; *(uint4*)(p + 4) = z;
    }
    const int wave = tid >> 6, lane = tid & 63;
#pragma unroll 4
    for (int rr = 0; rr < 4; ++rr) {
      const int i = f2 * 16 + wave * 4 + rr;
      const unsigned short* row = xb + (size_t)i * 1024;
      float acc = 0.f;
#pragma unroll 2
      for (int it = 0; it < 2; ++it) {
        const int k0 = (it * 64 + lane) * 8;
        bf16x8 pk = *(const bf16x8*)(row + k0);
#pragma unroll
        for (int j = 0; j < 8; ++j)
          acc += bf2f(((const unsigned short*)&pk)[j]) * w21[k0 + j];
      }
#pragma unroll
      for (int o = 32; o; o >>= 1) acc += __shfl_xor(acc, o);
      if (lane == 0) vvec[i] = acc;
    }
  } else {
    const int e = (f - 640) * 4 + (tid >> 6);
    const int lane = tid & 63;
    float acc = 0.f;
#pragma unroll 4
    for (int i = 0; i < 16; ++i) {
      const int j = i * 64 + lane;
      acc += bf2f(W4t[(size_t)e * 1024 + j]) * b3[j];
    }
#pragma unroll
    for (int o = 32; o; o >>= 1) acc += __shfl_xor(acc, o);
    if (lane == 0) bfv[e] = acc + b4[e];
  }
}

// ---------------------------------------------------------------------------
extern "C" void kernel_launch(void* const* d_in, const int* in_sizes, int n_in,
                              void* d_out, int out_size, void* d_ws, size_t ws_size,
                              hipStream_t stream)
{
  const float* x  = (const float*)d_in[0];
  const float* W1 = (const float*)d_in[1];
  const float* b1 = (const float*)d_in[2];
  const float* W2 = (const float*)d_in[3];
  // b2 unused: cancels in softmax (row-constant terms)
  const float* W3 = (const float*)d_in[5];
  const float* b3 = (const float*)d_in[6];
  const float* W4 = (const float*)d_in[7];
  const float* b4 = (const float*)d_in[8];

  char* ws = (char*)d_ws;
  const size_t MB = 1024 * 1024;
  unsigned short* xb    = (unsigned short*)(ws);            // 16MB
  unsigned short* W4t   = (unsigned short*)(ws + 16 * MB);  // 2MB
  unsigned short* W2b   = (unsigned short*)(ws + 18 * MB);  // 2MB
  unsigned short* W1b   = (unsigned short*)(ws + 20 * MB);  // 2MB
  unsigned short* W3b   = (unsigned short*)(ws + 22 * MB);  // 2MB
  unsigned short* G     = (unsigned short*)(ws + 24 * MB);  // 16MB: x @ M
  unsigned short* Mtb   = (unsigned short*)(ws + 40 * MB);  // 2MB
  unsigned short* W34tb = (unsigned short*)(ws + 42 * MB);  // 2MB
  float*          rsum  = (float*)(ws + 44 * MB);           // 32KB
  float*          bfv   = (float*)(ws + 45 * MB);           // 4KB
  float*          w21   = (float*)(ws + 45 * MB + 8192);    // 4KB
  float*          vvec  = (float*)(ws + 45 * MB + 16384);   // 32KB
  unsigned short* Vt    = (unsigned short*)(ws + 56 * MB);  // 16MB
  unsigned short* S     = (unsigned short*)(ws + 72 * MB);  // 32MB exp values

  // 1. x/W converts, W4 transpose, w21
  bigprep<<<6144, 256, 0, stream>>>(x, W1, W2, W3, W4, b1,
                                    xb, W1b, W2b, W3b, W4t, w21);

  // 2. Mtb/W34tb GEMMs + v-vector + rsum zero + bfv
  prep2<<<896, 256, 0, stream>>>(W2b, W1b, W4t, W3b, Mtb, W34tb,
                                 xb, w21, b3, b4, vvec, rsum, bfv);

  // 3. G = xb @ Mtb^T   [8192][1024]                        (256 blocks)
  gemm256<128, 0, false><<<dim3(8, 32, 1), 512, 0, stream>>>(
      xb, Mtb, nullptr, nullptr, G, 1024, 1024, 1024, 1024, 1.f, 0, 0, 0);

  // 4. Vt[z][e][t] = sum_k W34tb[e][k] * xb[z][t][k]        (256 blocks)
  gemm256<128, 0, false><<<dim3(16, 4, 4), 512, 0, stream>>>(
      W34tb, xb, nullptr, nullptr, Vt, 1024, 1024, 1024, 2048, 1.f,
      0, 2048L * 1024, 1024L * 2048);

  // 5. S[z] = exp((G[z] @ xb[z]^T + v[col]) / 32), rowsum -> rsum
  gemm256<256, 3, false><<<dim3(8, 8, 4), 512, 0, stream>>>(
      G, xb, vvec, rsum, S, 1024, 1024, 1024, 2048, 0.03125f,
      2048L * 1024, 2048L * 1024, 2048L * 2048);

  // 6. out[z] = (S[z] @ V'[z]) * rcp(rsum[row]) + bfv[col]  (fp32)
  gemm256<128, 5, true><<<dim3(8, 8, 4), 512, 0, stream>>>(
      S, Vt, bfv, rsum, d_out, 2048, 2048, 2048, 1024, 1.f,
      2048L * 2048, 1024L * 2048, 2048L * 1024);
}

// Round 10
// 167.755 us; speedup vs baseline: 1.1690x; 1.0095x over previous
//
#include <hip/hip_runtime.h>
#include <hip/hip_bf16.h>

typedef __attribute__((ext_vector_type(4))) float f32x4;
typedef __attribute__((ext_vector_type(8))) short bf16x8;

__device__ __forceinline__ void gload_lds16(const void* g, void* l) {
  __builtin_amdgcn_global_load_lds(
      (const __attribute__((address_space(1))) void*)g,
      (__attribute__((address_space(3))) void*)l, 16, 0, 0);
}

__device__ __forceinline__ unsigned short f2bf(float f) {
  union { float f; unsigned u; } x; x.f = f;
  unsigned r = x.u + 0x7fffu + ((x.u >> 16) & 1u);
  return (unsigned short)(r >> 16);
}

__device__ __forceinline__ float bf2f(unsigned short s) {
  union { unsigned u; float f; } x; x.u = (unsigned)s << 16;
  return x.f;
}

template<int N> __device__ __forceinline__ void vm_wait();
template<> __device__ __forceinline__ void vm_wait<0>() { asm volatile("s_waitcnt vmcnt(0)" ::: "memory"); }
template<> __device__ __forceinline__ void vm_wait<4>() { asm volatile("s_waitcnt vmcnt(4)" ::: "memory"); }
template<> __device__ __forceinline__ void vm_wait<6>() { asm volatile("s_waitcnt vmcnt(6)" ::: "memory"); }

#define BARRIER() asm volatile("s_barrier" ::: "memory")
#define SCHED0()  __builtin_amdgcn_sched_barrier(0)

// ---------------------------------------------------------------------------
// 256xBN 8-phase double-buffered GEMM body: C = f(alpha * A[M][K] @ Bt[N][K]^T)
// EPI: 0 = alpha only,
//      3 = exp(alpha*(acc + bias[bz*2048+col])) + atomic per-row sum into rs,
//      5 = acc * rcp(rs[row]) + bias[col].
// 512 threads, BK=64, T2 LDS swizzle, T4 counted vmcnt, T5 setprio.
// ---------------------------------------------------------------------------
template<int BN, int EPI, bool OUT_F32>
__device__ __forceinline__ void gemm_body(
    const unsigned short* __restrict__ A,
    const unsigned short* __restrict__ Bt,
    const float* __restrict__ bias,
    float* __restrict__ rs,
    void* __restrict__ Cout,
    int K, int lda, int ldb, int ldc, float alpha,
    long sA, long sB, long sC,
    int bx, int by, int bz, unsigned short* lds)
{
  constexpr int THREADS = 512;
  constexpr int WN = BN / 64;
  constexpr int WM = 8 / WN;
  constexpr int WTM = 256 / WM;
  constexpr int M_REP = WTM / 16;
  constexpr int MH = M_REP / 2;
  constexpr int ABUFE = 256 * 64;
  constexpr int BBUFE = BN * 64;
  constexpr int BBASE = 2 * ABUFE;
  constexpr int LOADS_A = 2;
  constexpr int LOADS_B = BN / 128;
  constexpr int VM_STEADY = 2 * LOADS_B + LOADS_A;  // 6 or 4

  const int tid = threadIdx.x, wave = tid >> 6, lane = tid & 63;
  const int wr = wave / WN, wc = wave % WN;
  const int fr = lane & 15, fq = lane >> 4, sw = fr & 7;

  A  += (size_t)bz * sA;
  Bt += (size_t)bz * sB;
  const int m0 = by * 256;
  const int n0 = bx * BN;
  const int NT = K >> 6;

  f32x4 acc[M_REP][4] = {};
  bf16x8 a[MH][2], b[4][2];

  auto stageA = [&](int t, int half) {
#pragma unroll
    for (int c = 0; c < LOADS_A; ++c) {
      const int s = c * THREADS + tid;
      const int rr = s >> 3;
      const int col = ((tid & 7) ^ (rr & 7)) * 8;
      gload_lds16(A + (size_t)(m0 + half * 128 + rr) * lda + t * 64 + col,
                  &lds[(t & 1) * ABUFE + half * (128 * 64) + s * 8]);
    }
  };
  auto stageB = [&](int t, int half) {
#pragma unroll
    for (int c = 0; c < LOADS_B; ++c) {
      const int s = c * THREADS + tid;
      const int rr = s >> 3;
      const int col = ((tid & 7) ^ (rr & 7)) * 8;
      gload_lds16(Bt + (size_t)(n0 + half * (BN / 2) + rr) * ldb + t * 64 + col,
                  &lds[BBASE + (t & 1) * BBUFE + half * ((BN / 2) * 64) + s * 8]);
    }
  };
  auto readA = [&](int buf, int mq) {
    const unsigned short* p = &lds[buf * ABUFE];
#pragma unroll
    for (int mm = 0; mm < MH; ++mm)
#pragma unroll
      for (int kk = 0; kk < 2; ++kk)
        a[mm][kk] = *(const bf16x8*)(p + (wr * WTM + mq * (WTM / 2) + mm * 16 + fr) * 64
                                       + ((kk * 4 + fq) ^ sw) * 8);
  };
  auto readB = [&](int buf, int nh) {
    const unsigned short* p = &lds[BBASE + buf * BBUFE];
#pragma unroll
    for (int nn = 0; nn < 2; ++nn)
#pragma unroll
      for (int kk = 0; kk < 2; ++kk)
        b[nh * 2 + nn][kk] = *(const bf16x8*)(p + (wc * 64 + (nh * 2 + nn) * 16 + fr) * 64
                                                + ((kk * 4 + fq) ^ sw) * 8);
  };
  auto mfmaQ = [&](int mq, int nh) {
    __builtin_amdgcn_s_setprio(1);
#pragma unroll
    for (int kk = 0; kk < 2; ++kk)
#pragma unroll
      for (int mm = 0; mm < MH; ++mm)
#pragma unroll
        for (int nn = 0; nn < 2; ++nn)
          acc[mq * MH + mm][nh * 2 + nn] = __builtin_amdgcn_mfma_f32_16x16x32_bf16(
              a[mm][kk], b[nh * 2 + nn][kk], acc[mq * MH + mm][nh * 2 + nn], 0, 0, 0);
    __builtin_amdgcn_s_setprio(0);
  };

  // prologue: tile0 fully, tile1 {B0,B1,A0}
  stageA(0, 0); stageA(0, 1); stageB(0, 0); stageB(0, 1);
  if (NT > 1) { stageB(1, 0); stageB(1, 1); stageA(1, 0); vm_wait<VM_STEADY>(); }
  else        { vm_wait<0>(); }
  BARRIER();

#pragma unroll 2
  for (int t = 0; t < NT; ++t) {
    const int buf = t & 1;
    // ph1
    readA(buf, 0); readB(buf, 0);
    BARRIER(); SCHED0();
    mfmaQ(0, 0);
    SCHED0();
    BARRIER();
    // ph2
    readB(buf, 1);
    if (t + 1 < NT) stageA(t + 1, 1);
    BARRIER(); SCHED0();
    mfmaQ(0, 1);
    SCHED0();
    BARRIER();
    // ph3
    readA(buf, 1);
    if (t + 2 < NT) stageB(t + 2, 0);
    BARRIER(); SCHED0();
    mfmaQ(1, 0);
    SCHED0();
    BARRIER();
    // ph4
    if (t + 2 < NT) { stageB(t + 2, 1); stageA(t + 2, 0); vm_wait<VM_STEADY>(); }
    else            { vm_wait<0>(); }
    BARRIER(); SCHED0();
    mfmaQ(1, 1);
    SCHED0();
    BARRIER();
  }

  // epilogue (nn innermost for L2 write combining)
  float bvc[4];
  if (EPI == 5) {
#pragma unroll
    for (int nn = 0; nn < 4; ++nn) bvc[nn] = bias[n0 + wc * 64 + nn * 16 + fr];
  }
  if (EPI == 3) {
#pragma unroll
    for (int nn = 0; nn < 4; ++nn)
      bvc[nn] = bias[(size_t)bz * 2048 + n0 + wc * 64 + nn * 16 + fr];
  }
#pragma unroll
  for (int mm = 0; mm < M_REP; ++mm) {
    const int rbase = m0 + wr * WTM + mm * 16 + fq * 4;
#pragma unroll
    for (int j = 0; j < 4; ++j) {
      const int row = rbase + j;
      float rsc = 1.f;
      if (EPI == 5) rsc = __builtin_amdgcn_rcpf(rs[(size_t)bz * 2048 + row]);
      float part = 0.f;
#pragma unroll
      for (int nn = 0; nn < 4; ++nn) {
        const int col = n0 + wc * 64 + nn * 16 + fr;
        float v = acc[mm][nn][j];
        if      (EPI == 3) { v = __expf((v + bvc[nn]) * alpha); part += v; }
        else if (EPI == 5) v = v * rsc + bvc[nn];
        else               v = v * alpha;
        const size_t off = (size_t)bz * sC + (size_t)row * ldc + col;
        if (OUT_F32) ((float*)Cout)[off] = v;
        else         ((unsigned short*)Cout)[off] = f2bf(v);
      }
      if (EPI == 3) {
        part += __shfl_xor(part, 1); part += __shfl_xor(part, 2);
        part += __shfl_xor(part, 4); part += __shfl_xor(part, 8);
        if (fr == 0) atomicAdd(rs + (size_t)bz * 2048 + row, part);
      }
    }
  }
}

// bijective XCD-chunked swizzle over nwg blocks
__device__ __forceinline__ int xcd_swz(int lid, int nwg) {
  const int q = nwg >> 3, r = nwg & 7;
  const int xcd = lid & 7, idx = lid >> 3;
  return (xcd < r ? xcd * (q + 1) : r * (q + 1) + (xcd - r) * q) + idx;
}

// ---------------------------------------------------------------------------
template<int BN, int EPI, bool OUT_F32>
__global__ __launch_bounds__(512, 2)
void gemm256(const unsigned short* __restrict__ A,
             const unsigned short* __restrict__ Bt,
             const float* __restrict__ bias,
             float* __restrict__ rs,
             void* __restrict__ Cout,
             int K, int lda, int ldb, int ldc, float alpha,
             long sA, long sB, long sC)
{
  __shared__ __attribute__((aligned(16))) unsigned short lds[2 * 256 * 64 + 2 * BN * 64];
  const int gx = gridDim.x, gy = gridDim.y;
  const int lid = blockIdx.x + gx * (blockIdx.y + gy * blockIdx.z);
  const int nl = xcd_swz(lid, gx * gy * gridDim.z);
  const int bx = nl % gx, by = (nl / gx) % gy, bz = nl / (gx * gy);
  gemm_body<BN, EPI, OUT_F32>(A, Bt, bias, rs, Cout, K, lda, ldb, ldc, alpha,
                              sA, sB, sC, bx, by, bz, lds);
}

// dual launch: blocks [0,256) = G-proj (grid 8x32x1), [256,512) = Vt-proj (16x4x4)
__global__ __launch_bounds__(512, 2)
void gemm256_dual(const unsigned short* __restrict__ A0, const unsigned short* __restrict__ B0,
                  void* __restrict__ C0,
                  const unsigned short* __restrict__ A1, const unsigned short* __restrict__ B1,
                  void* __restrict__ C1,
                  long sA1, long sB1, long sC1)
{
  __shared__ __attribute__((aligned(16))) unsigned short lds[2 * 256 * 64 + 2 * 128 * 64];
  const int f = blockIdx.x;
  if (f < 256) {
    const int nl = xcd_swz(f, 256);
    const int bx = nl & 7, by = nl >> 3;   // gx=8, gy=32
    gemm_body<128, 0, false>(A0, B0, nullptr, nullptr, C0,
                             1024, 1024, 1024, 1024, 1.f, 0, 0, 0, bx, by, 0, lds);
  } else {
    const int nl = xcd_swz(f - 256, 256);
    const int bx = nl & 15, by = (nl >> 4) & 3, bz = nl >> 6;  // gx=16, gy=4, gz=4
    gemm_body<128, 0, false>(A1, B1, nullptr, nullptr, C1,
                             1024, 1024, 1024, 2048, 1.f, sA1, sB1, sC1, bx, by, bz, lds);
  }
}

// ---------------------------------------------------------------------------
// bigprep, flat grid 6144 blocks x 256 threads:
//  [0,4096)    : x fp32 -> bf16 (2048 elems/block)
//  [4096,5632) : convert W1/W2/W3 fp32->bf16 (512 blocks each)
//  [5632,5888) : transpose W4 -> W4t bf16 [e][j]
//  [5888,6144) : w21[f] = sum_n W2[f][n]*b1[n]  (fp32 reads)
// ---------------------------------------------------------------------------
__global__ __launch_bounds__(256)
void bigprep(const float* __restrict__ x,
             const float* __restrict__ W1, const float* __restrict__ W2,
             const float* __restrict__ W3, const float* __restrict__ W4,
             const float* __restrict__ b1,
             unsigned short* __restrict__ xb,
             unsigned short* __restrict__ W1b, unsigned short* __restrict__ W2b,
             unsigned short* __restrict__ W3b, unsigned short* __restrict__ W4t,
             float* __restrict__ w21)
{
  __shared__ float t[64][65];
  const int f = blockIdx.x, tid = threadIdx.x;
  if (f < 5632) {
    const float* src;
    unsigned short* dst;
    int blk;
    if (f < 4096) { src = x; dst = xb; blk = f; }
    else {
      const int which = (f - 4096) >> 9;
      blk = (f - 4096) & 511;
      src = (which == 0) ? W1 : (which == 1) ? W2 : W3;
      dst = (which == 0) ? W1b : (which == 1) ? W2b : W3b;
    }
    const int idx = (blk * 256 + tid) * 8;
    const float4 p = *(const float4*)(src + idx);
    const float4 q = *(const float4*)(src + idx + 4);
    unsigned u0 = (unsigned)f2bf(p.x) | ((unsigned)f2bf(p.y) << 16);
    unsigned u1 = (unsigned)f2bf(p.z) | ((unsigned)f2bf(p.w) << 16);
    unsigned u2 = (unsigned)f2bf(q.x) | ((unsigned)f2bf(q.y) << 16);
    unsigned u3 = (unsigned)f2bf(q.z) | ((unsigned)f2bf(q.w) << 16);
    uint4 o; o.x = u0; o.y = u1; o.z = u2; o.w = u3;
    *(uint4*)(dst + idx) = o;
  } else if (f < 5888) {
    const int tb = f - 5632;
    const int k0 = (tb >> 4) * 64, n0 = (tb & 15) * 64;
    const int tx = tid & 63, ty = tid >> 6;
#pragma unroll
    for (int r = ty; r < 64; r += 4)
      t[r][tx] = W4[(size_t)(k0 + r) * 1024 + n0 + tx];
    __syncthreads();
#pragma unroll
    for (int r = ty; r < 64; r += 4)
      W4t[(size_t)(n0 + r) * 1024 + k0 + tx] = f2bf(t[tx][r]);
  } else {
    const int e = (f - 5888) * 4 + (tid >> 6);
    const int lane = tid & 63;
    float acc = 0.f;
#pragma unroll 4
    for (int i = 0; i < 16; ++i) {
      const int n = i * 64 + lane;
      acc += W2[(size_t)e * 1024 + n] * b1[n];
    }
#pragma unroll
    for (int o = 32; o; o >>= 1) acc += __shfl_xor(acc, o);
    if (lane == 0) w21[e] = acc;
  }
}

// ---------------------------------------------------------------------------
// prep2, flat grid 896 blocks x 256 threads:
//  [0,128)   : Mtb = W2b @ W1b^T (z=0) / W34tb = W4t @ W3b^T (z=1), 128^2 tile
//  [128,640) : v[i] = xb[i].w21 (16 rows/block); blocks 128..131 also zero rsum
//  [640,896) : bfv[e] = b4[e] + sum_j b3[j]*W4t[e][j]  (coalesced bf16 rows)
// ---------------------------------------------------------------------------
__global__ __launch_bounds__(256, 2)
void prep2(const unsigned short* __restrict__ W2b, const unsigned short* __restrict__ W1b,
           const unsigned short* __restrict__ W4t, const unsigned short* __restrict__ W3b,
           unsigned short* __restrict__ Mtb, unsigned short* __restrict__ W34tb,
           const unsigned short* __restrict__ xb, const float* __restrict__ w21,
           const float* __restrict__ b3, const float* __restrict__ b4,
           float* __restrict__ vvec, float* __restrict__ rsum, float* __restrict__ bfv)
{
  __shared__ __attribute__((aligned(16))) unsigned short As[128 * 32];
  __shared__ __attribute__((aligned(16))) unsigned short Bs[128 * 32];
  const int f = blockIdx.x, tid = threadIdx.x;
  if (f < 128) {
    const int which = f >> 6, blk = f & 63;
    const unsigned short* A  = which ? W4t : W2b;
    const unsigned short* Bt = which ? W3b : W1b;
    unsigned short* C = which ? W34tb : Mtb;
    const int m0 = (blk >> 3) * 128, n0 = (blk & 7) * 128;
    const int wave = tid >> 6, lane = tid & 63;
    f32x4 acc[4][4] = {};
    const int wr = wave >> 1, wc = wave & 1;
    const int fr = lane & 15, fq = lane >> 4;
    const int si0 = wave * 2, sr = lane >> 2, sce = (lane & 3) * 8;
    for (int k0 = 0; k0 < 1024; k0 += 32) {
#pragma unroll
      for (int c = 0; c < 2; ++c) {
        const int i = si0 + c, rr = i * 16 + sr;
        gload_lds16(A  + (size_t)(m0 + rr) * 1024 + k0 + sce, As + i * 512 + lane * 8);
        gload_lds16(Bt + (size_t)(n0 + rr) * 1024 + k0 + sce, Bs + i * 512 + lane * 8);
      }
      __syncthreads();
      bf16x8 af[4], bg[4];
#pragma unroll
      for (int m = 0; m < 4; ++m)
        af[m] = *(const bf16x8*)(As + (wr * 64 + m * 16 + fr) * 32 + fq * 8);
#pragma unroll
      for (int n = 0; n < 4; ++n)
        bg[n] = *(const bf16x8*)(Bs + (wc * 64 + n * 16 + fr) * 32 + fq * 8);
#pragma unroll
      for (int m = 0; m < 4; ++m)
#pragma unroll
        for (int n = 0; n < 4; ++n)
          acc[m][n] = __builtin_amdgcn_mfma_f32_16x16x32_bf16(af[m], bg[n], acc[m][n], 0, 0, 0);
      __syncthreads();
    }
#pragma unroll
    for (int m = 0; m < 4; ++m) {
      const int rbase = m0 + wr * 64 + m * 16 + fq * 4;
#pragma unroll
      for (int j = 0; j < 4; ++j)
#pragma unroll
        for (int n = 0; n < 4; ++n)
          C[(size_t)(rbase + j) * 1024 + (n0 + wc * 64 + n * 16 + fr)] = f2bf(acc[m][n][j]);
    }
  } else if (f < 640) {
    const int f2 = f - 128;
    if (f2 < 4) {
      uint4 z = {0, 0, 0, 0};
      float* p = rsum + f2 * 2048 + tid * 8;
      *(uint4*)p = z; *(uint4*)(p + 4) = z;
    }
    const int wave = tid >> 6, lane = tid & 63;
#pragma unroll 4
    for (int rr = 0; rr < 4; ++rr) {
      const int i = f2 * 16 + wave * 4 + rr;
      const unsigned short* row = xb + (size_t)i * 1024;
      float acc = 0.f;
#pragma unroll 2
      for (int it = 0; it < 2; ++it) {
        const int k0 = (it * 64 + lane) * 8;
        bf16x8 pk = *(const bf16x8*)(row + k0);
#pragma unroll
        for (int j = 0; j < 8; ++j)
          acc += bf2f(((const unsigned short*)&pk)[j]) * w21[k0 + j];
      }
#pragma unroll
      for (int o = 32; o; o >>= 1) acc += __shfl_xor(acc, o);
      if (lane == 0) vvec[i] = acc;
    }
  } else {
    const int e = (f - 640) * 4 + (tid >> 6);
    const int lane = tid & 63;
    float acc = 0.f;
#pragma unroll 4
    for (int i = 0; i < 16; ++i) {
      const int j = i * 64 + lane;
      acc += bf2f(W4t[(size_t)e * 1024 + j]) * b3[j];
    }
#pragma unroll
    for (int o = 32; o; o >>= 1) acc += __shfl_xor(acc, o);
    if (lane == 0) bfv[e] = acc + b4[e];
  }
}

// ---------------------------------------------------------------------------
extern "C" void kernel_launch(void* const* d_in, const int* in_sizes, int n_in,
                              void* d_out, int out_size, void* d_ws, size_t ws_size,
                              hipStream_t stream)
{
  const float* x  = (const float*)d_in[0];
  const float* W1 = (const float*)d_in[1];
  const float* b1 = (const float*)d_in[2];
  const float* W2 = (const float*)d_in[3];
  // b2 unused: cancels in softmax (row-constant terms)
  const float* W3 = (const float*)d_in[5];
  const float* b3 = (const float*)d_in[6];
  const float* W4 = (const float*)d_in[7];
  const float* b4 = (const float*)d_in[8];

  char* ws = (char*)d_ws;
  const size_t MB = 1024 * 1024;
  unsigned short* xb    = (unsigned short*)(ws);            // 16MB
  unsigned short* W4t   = (unsigned short*)(ws + 16 * MB);  // 2MB
  unsigned short* W2b   = (unsigned short*)(ws + 18 * MB);  // 2MB
  unsigned short* W1b   = (unsigned short*)(ws + 20 * MB);  // 2MB
  unsigned short* W3b   = (unsigned short*)(ws + 22 * MB);  // 2MB
  unsigned short* G     = (unsigned short*)(ws + 24 * MB);  // 16MB: x @ M
  unsigned short* Mtb   = (unsigned short*)(ws + 40 * MB);  // 2MB
  unsigned short* W34tb = (unsigned short*)(ws + 42 * MB);  // 2MB
  float*          rsum  = (float*)(ws + 44 * MB);           // 32KB
  float*          bfv   = (float*)(ws + 45 * MB);           // 4KB
  float*          w21   = (float*)(ws + 45 * MB + 8192);    // 4KB
  float*          vvec  = (float*)(ws + 45 * MB + 16384);   // 32KB
  unsigned short* Vt    = (unsigned short*)(ws + 56 * MB);  // 16MB
  unsigned short* S     = (unsigned short*)(ws + 72 * MB);  // 32MB exp values

  // 1. x/W converts, W4 transpose, w21
  bigprep<<<6144, 256, 0, stream>>>(x, W1, W2, W3, W4, b1,
                                    xb, W1b, W2b, W3b, W4t, w21);

  // 2. Mtb/W34tb GEMMs + v-vector + rsum zero + bfv
  prep2<<<896, 256, 0, stream>>>(W2b, W1b, W4t, W3b, Mtb, W34tb,
                                 xb, w21, b3, b4, vvec, rsum, bfv);

  // 3. G = xb @ Mtb^T  [8192][1024]  ||  Vt[z] = W34tb @ xb[z]^T  [4][1024][2048]
  gemm256_dual<<<512, 512, 0, stream>>>(xb, Mtb, G, W34tb, xb, Vt,
                                        0, 2048L * 1024, 1024L * 2048);

  // 4. S[z] = exp((G[z] @ xb[z]^T + v[col]) / 32), rowsum -> rsum
  gemm256<256, 3, false><<<dim3(8, 8, 4), 512, 0, stream>>>(
      G, xb, vvec, rsum, S, 1024, 1024, 1024, 2048, 0.03125f,
      2048L * 1024, 2048L * 1024, 2048L * 2048);

  // 5. out[z] = (S[z] @ V'[z]) * rcp(rsum[row]) + bfv[col]  (fp32)
  gemm256<128, 5, true><<<dim3(8, 8, 4), 512, 0, stream>>>(
      S, Vt, bfv, rsum, d_out, 2048, 2048, 2048, 1024, 1.f,
      2048L * 2048, 1024L * 2048, 2048L * 1024);
}

// Round 11
// 162.298 us; speedup vs baseline: 1.2083x; 1.0336x over previous
//
#include <hip/hip_runtime.h>
#include <hip/hip_bf16.h>

typedef __attribute__((ext_vector_type(4))) float f32x4;
typedef __attribute__((ext_vector_type(8))) short bf16x8;

__device__ __forceinline__ void gload_lds16(const void* g, void* l) {
  __builtin_amdgcn_global_load_lds(
      (const __attribute__((address_space(1))) void*)g,
      (__attribute__((address_space(3))) void*)l, 16, 0, 0);
}

__device__ __forceinline__ unsigned short f2bf(float f) {
  union { float f; unsigned u; } x; x.f = f;
  unsigned r = x.u + 0x7fffu + ((x.u >> 16) & 1u);
  return (unsigned short)(r >> 16);
}

__device__ __forceinline__ float bf2f(unsigned short s) {
  union { unsigned u; float f; } x; x.u = (unsigned)s << 16;
  return x.f;
}

template<int N> __device__ __forceinline__ void vm_wait();
template<> __device__ __forceinline__ void vm_wait<0>() { asm volatile("s_waitcnt vmcnt(0)" ::: "memory"); }
template<> __device__ __forceinline__ void vm_wait<4>() { asm volatile("s_waitcnt vmcnt(4)" ::: "memory"); }
template<> __device__ __forceinline__ void vm_wait<6>() { asm volatile("s_waitcnt vmcnt(6)" ::: "memory"); }

#define BARRIER() asm volatile("s_barrier" ::: "memory")
#define SCHED0()  __builtin_amdgcn_sched_barrier(0)

// ---------------------------------------------------------------------------
// 256xBN 8-phase double-buffered GEMM body: C = f(alpha * A[M][K] @ Bt[N][K]^T)
// K / LDA / LDB / LDC are compile-time: all LDS + fragment addresses constant-
// fold; NT-loop branches are constexpr-bounded.
// EPI: 0 = alpha only,
//      3 = exp(alpha*(acc + bias[bz*2048+col])) + atomic per-row sum into rs,
//      5 = acc * rcp(rs[row]) + bias[col].
// 512 threads, BK=64, T2 LDS swizzle, T4 counted vmcnt, T5 setprio.
// ---------------------------------------------------------------------------
template<int BN, int EPI, bool OUT_F32, int K, int LDA, int LDB, int LDC>
__device__ __forceinline__ void gemm_body(
    const unsigned short* __restrict__ A,
    const unsigned short* __restrict__ Bt,
    const float* __restrict__ bias,
    float* __restrict__ rs,
    void* __restrict__ Cout,
    float alpha, long sA, long sB, long sC,
    int bx, int by, int bz, unsigned short* lds)
{
  constexpr int THREADS = 512;
  constexpr int WN = BN / 64;
  constexpr int WM = 8 / WN;
  constexpr int WTM = 256 / WM;
  constexpr int M_REP = WTM / 16;
  constexpr int MH = M_REP / 2;
  constexpr int ABUFE = 256 * 64;
  constexpr int BBUFE = BN * 64;
  constexpr int BBASE = 2 * ABUFE;
  constexpr int LOADS_A = 2;
  constexpr int LOADS_B = BN / 128;
  constexpr int VM_STEADY = 2 * LOADS_B + LOADS_A;  // 6 or 4
  constexpr int NT = K >> 6;

  const int tid = threadIdx.x, wave = tid >> 6, lane = tid & 63;
  const int wr = wave / WN, wc = wave % WN;
  const int fr = lane & 15, fq = lane >> 4, sw = fr & 7;

  A  += (size_t)bz * sA;
  Bt += (size_t)bz * sB;
  const int m0 = by * 256;
  const int n0 = bx * BN;

  f32x4 acc[M_REP][4] = {};
  bf16x8 a[MH][2], b[4][2];

  auto stageA = [&](int t, int half) {
#pragma unroll
    for (int c = 0; c < LOADS_A; ++c) {
      const int s = c * THREADS + tid;
      const int rr = s >> 3;
      const int col = ((tid & 7) ^ (rr & 7)) * 8;
      gload_lds16(A + (size_t)(m0 + half * 128 + rr) * LDA + t * 64 + col,
                  &lds[(t & 1) * ABUFE + half * (128 * 64) + s * 8]);
    }
  };
  auto stageB = [&](int t, int half) {
#pragma unroll
    for (int c = 0; c < LOADS_B; ++c) {
      const int s = c * THREADS + tid;
      const int rr = s >> 3;
      const int col = ((tid & 7) ^ (rr & 7)) * 8;
      gload_lds16(Bt + (size_t)(n0 + half * (BN / 2) + rr) * LDB + t * 64 + col,
                  &lds[BBASE + (t & 1) * BBUFE + half * ((BN / 2) * 64) + s * 8]);
    }
  };
  auto readA = [&](int buf, int mq) {
    const unsigned short* p = &lds[buf * ABUFE];
#pragma unroll
    for (int mm = 0; mm < MH; ++mm)
#pragma unroll
      for (int kk = 0; kk < 2; ++kk)
        a[mm][kk] = *(const bf16x8*)(p + (wr * WTM + mq * (WTM / 2) + mm * 16 + fr) * 64
                                       + ((kk * 4 + fq) ^ sw) * 8);
  };
  auto readB = [&](int buf, int nh) {
    const unsigned short* p = &lds[BBASE + buf * BBUFE];
#pragma unroll
    for (int nn = 0; nn < 2; ++nn)
#pragma unroll
      for (int kk = 0; kk < 2; ++kk)
        b[nh * 2 + nn][kk] = *(const bf16x8*)(p + (wc * 64 + (nh * 2 + nn) * 16 + fr) * 64
                                                + ((kk * 4 + fq) ^ sw) * 8);
  };
  auto mfmaQ = [&](int mq, int nh) {
    __builtin_amdgcn_s_setprio(1);
#pragma unroll
    for (int kk = 0; kk < 2; ++kk)
#pragma unroll
      for (int mm = 0; mm < MH; ++mm)
#pragma unroll
        for (int nn = 0; nn < 2; ++nn)
          acc[mq * MH + mm][nh * 2 + nn] = __builtin_amdgcn_mfma_f32_16x16x32_bf16(
              a[mm][kk], b[nh * 2 + nn][kk], acc[mq * MH + mm][nh * 2 + nn], 0, 0, 0);
    __builtin_amdgcn_s_setprio(0);
  };

  // prologue: tile0 fully, tile1 {B0,B1,A0}
  stageA(0, 0); stageA(0, 1); stageB(0, 0); stageB(0, 1);
  if (NT > 1) { stageB(1, 0); stageB(1, 1); stageA(1, 0); vm_wait<VM_STEADY>(); }
  else        { vm_wait<0>(); }
  BARRIER();

#pragma unroll 2
  for (int t = 0; t < NT; ++t) {
    const int buf = t & 1;
    // ph1
    readA(buf, 0); readB(buf, 0);
    BARRIER(); SCHED0();
    mfmaQ(0, 0);
    SCHED0();
    BARRIER();
    // ph2
    readB(buf, 1);
    if (t + 1 < NT) stageA(t + 1, 1);
    BARRIER(); SCHED0();
    mfmaQ(0, 1);
    SCHED0();
    BARRIER();
    // ph3
    readA(buf, 1);
    if (t + 2 < NT) stageB(t + 2, 0);
    BARRIER(); SCHED0();
    mfmaQ(1, 0);
    SCHED0();
    BARRIER();
    // ph4
    if (t + 2 < NT) { stageB(t + 2, 1); stageA(t + 2, 0); vm_wait<VM_STEADY>(); }
    else            { vm_wait<0>(); }
    BARRIER(); SCHED0();
    mfmaQ(1, 1);
    SCHED0();
    BARRIER();
  }

  // epilogue (nn innermost for L2 write combining)
  float bvc[4];
  if (EPI == 5) {
#pragma unroll
    for (int nn = 0; nn < 4; ++nn) bvc[nn] = bias[n0 + wc * 64 + nn * 16 + fr];
  }
  if (EPI == 3) {
#pragma unroll
    for (int nn = 0; nn < 4; ++nn)
      bvc[nn] = bias[(size_t)bz * 2048 + n0 + wc * 64 + nn * 16 + fr];
  }
#pragma unroll
  for (int mm = 0; mm < M_REP; ++mm) {
    const int rbase = m0 + wr * WTM + mm * 16 + fq * 4;
#pragma unroll
    for (int j = 0; j < 4; ++j) {
      const int row = rbase + j;
      float rsc = 1.f;
      if (EPI == 5) rsc = __builtin_amdgcn_rcpf(rs[(size_t)bz * 2048 + row]);
      float part = 0.f;
#pragma unroll
      for (int nn = 0; nn < 4; ++nn) {
        const int col = n0 + wc * 64 + nn * 16 + fr;
        float v = acc[mm][nn][j];
        if      (EPI == 3) { v = __expf((v + bvc[nn]) * alpha); part += v; }
        else if (EPI == 5) v = v * rsc + bvc[nn];
        else               v = v * alpha;
        const size_t off = (size_t)bz * sC + (size_t)row * LDC + col;
        if (OUT_F32) ((float*)Cout)[off] = v;
        else         ((unsigned short*)Cout)[off] = f2bf(v);
      }
      if (EPI == 3) {
        part += __shfl_xor(part, 1); part += __shfl_xor(part, 2);
        part += __shfl_xor(part, 4); part += __shfl_xor(part, 8);
        if (fr == 0) atomicAdd(rs + (size_t)bz * 2048 + row, part);
      }
    }
  }
}

// bijective XCD-chunked swizzle over nwg blocks
__device__ __forceinline__ int xcd_swz(int lid, int nwg) {
  const int q = nwg >> 3, r = nwg & 7;
  const int xcd = lid & 7, idx = lid >> 3;
  return (xcd < r ? xcd * (q + 1) : r * (q + 1) + (xcd - r) * q) + idx;
}

// ---------------------------------------------------------------------------
template<int BN, int EPI, bool OUT_F32, int K, int LDA, int LDB, int LDC>
__global__ __launch_bounds__(512, 2)
void gemm256(const unsigned short* __restrict__ A,
             const unsigned short* __restrict__ Bt,
             const float* __restrict__ bias,
             float* __restrict__ rs,
             void* __restrict__ Cout,
             float alpha, long sA, long sB, long sC)
{
  __shared__ __attribute__((aligned(16))) unsigned short lds[2 * 256 * 64 + 2 * BN * 64];
  const int gx = gridDim.x, gy = gridDim.y;
  const int lid = blockIdx.x + gx * (blockIdx.y + gy * blockIdx.z);
  const int nl = xcd_swz(lid, gx * gy * gridDim.z);
  const int bx = nl % gx, by = (nl / gx) % gy, bz = nl / (gx * gy);
  gemm_body<BN, EPI, OUT_F32, K, LDA, LDB, LDC>(A, Bt, bias, rs, Cout, alpha,
                                                sA, sB, sC, bx, by, bz, lds);
}

// dual launch: blocks [0,256) = G-proj (grid 8x32x1), [256,512) = Vt-proj (16x4x4)
__global__ __launch_bounds__(512, 2)
void gemm256_dual(const unsigned short* __restrict__ A0, const unsigned short* __restrict__ B0,
                  void* __restrict__ C0,
                  const unsigned short* __restrict__ A1, const unsigned short* __restrict__ B1,
                  void* __restrict__ C1,
                  long sA1, long sB1, long sC1)
{
  __shared__ __attribute__((aligned(16))) unsigned short lds[2 * 256 * 64 + 2 * 128 * 64];
  const int f = blockIdx.x;
  if (f < 256) {
    const int nl = xcd_swz(f, 256);
    const int bx = nl & 7, by = nl >> 3;   // gx=8, gy=32
    gemm_body<128, 0, false, 1024, 1024, 1024, 1024>(
        A0, B0, nullptr, nullptr, C0, 1.f, 0, 0, 0, bx, by, 0, lds);
  } else {
    const int nl = xcd_swz(f - 256, 256);
    const int bx = nl & 15, by = (nl >> 4) & 3, bz = nl >> 6;  // gx=16, gy=4, gz=4
    gemm_body<128, 0, false, 1024, 1024, 1024, 2048>(
        A1, B1, nullptr, nullptr, C1, 1.f, sA1, sB1, sC1, bx, by, bz, lds);
  }
}

// ---------------------------------------------------------------------------
// bigprep, flat grid 6144 blocks x 256 threads:
//  [0,4096)    : x fp32 -> bf16 (2048 elems/block)
//  [4096,5632) : convert W1/W2/W3 fp32->bf16 (512 blocks each)
//  [5632,5888) : transpose W4 -> W4t bf16 [e][j]
//  [5888,6144) : w21[f] = sum_n W2[f][n]*b1[n]  (fp32 reads)
// ---------------------------------------------------------------------------
__global__ __launch_bounds__(256)
void bigprep(const float* __restrict__ x,
             const float* __restrict__ W1, const float* __restrict__ W2,
             const float* __restrict__ W3, const float* __restrict__ W4,
             const float* __restrict__ b1,
             unsigned short* __restrict__ xb,
             unsigned short* __restrict__ W1b, unsigned short* __restrict__ W2b,
             unsigned short* __restrict__ W3b, unsigned short* __restrict__ W4t,
             float* __restrict__ w21)
{
  __shared__ float t[64][65];
  const int f = blockIdx.x, tid = threadIdx.x;
  if (f < 5632) {
    const float* src;
    unsigned short* dst;
    int blk;
    if (f < 4096) { src = x; dst = xb; blk = f; }
    else {
      const int which = (f - 4096) >> 9;
      blk = (f - 4096) & 511;
      src = (which == 0) ? W1 : (which == 1) ? W2 : W3;
      dst = (which == 0) ? W1b : (which == 1) ? W2b : W3b;
    }
    const int idx = (blk * 256 + tid) * 8;
    const float4 p = *(const float4*)(src + idx);
    const float4 q = *(const float4*)(src + idx + 4);
    unsigned u0 = (unsigned)f2bf(p.x) | ((unsigned)f2bf(p.y) << 16);
    unsigned u1 = (unsigned)f2bf(p.z) | ((unsigned)f2bf(p.w) << 16);
    unsigned u2 = (unsigned)f2bf(q.x) | ((unsigned)f2bf(q.y) << 16);
    unsigned u3 = (unsigned)f2bf(q.z) | ((unsigned)f2bf(q.w) << 16);
    uint4 o; o.x = u0; o.y = u1; o.z = u2; o.w = u3;
    *(uint4*)(dst + idx) = o;
  } else if (f < 5888) {
    const int tb = f - 5632;
    const int k0 = (tb >> 4) * 64, n0 = (tb & 15) * 64;
    const int tx = tid & 63, ty = tid >> 6;
#pragma unroll
    for (int r = ty; r < 64; r += 4)
      t[r][tx] = W4[(size_t)(k0 + r) * 1024 + n0 + tx];
    __syncthreads();
#pragma unroll
    for (int r = ty; r < 64; r += 4)
      W4t[(size_t)(n0 + r) * 1024 + k0 + tx] = f2bf(t[tx][r]);
  } else {
    const int e = (f - 5888) * 4 + (tid >> 6);
    const int lane = tid & 63;
    float acc = 0.f;
#pragma unroll 4
    for (int i = 0; i < 16; ++i) {
      const int n = i * 64 + lane;
      acc += W2[(size_t)e * 1024 + n] * b1[n];
    }
#pragma unroll
    for (int o = 32; o; o >>= 1) acc += __shfl_xor(acc, o);
    if (lane == 0) w21[e] = acc;
  }
}

// ---------------------------------------------------------------------------
// prep2, flat grid 896 blocks x 256 threads:
//  [0,128)   : Mtb = W2b @ W1b^T (z=0) / W34tb = W4t @ W3b^T (z=1), 128^2 tile
//  [128,640) : v[i] = xb[i].w21 (16 rows/block); blocks 128..131 also zero rsum
//  [640,896) : bfv[e] = b4[e] + sum_j b3[j]*W4t[e][j]  (coalesced bf16 rows)
// ---------------------------------------------------------------------------
__global__ __launch_bounds__(256, 2)
void prep2(const unsigned short* __restrict__ W2b, const unsigned short* __restrict__ W1b,
           const unsigned short* __restrict__ W4t, const unsigned short* __restrict__ W3b,
           unsigned short* __restrict__ Mtb, unsigned short* __restrict__ W34tb,
           const unsigned short* __restrict__ xb, const float* __restrict__ w21,
           const float* __restrict__ b3, const float* __restrict__ b4,
           float* __restrict__ vvec, float* __restrict__ rsum, float* __restrict__ bfv)
{
  __shared__ __attribute__((aligned(16))) unsigned short As[128 * 32];
  __shared__ __attribute__((aligned(16))) unsigned short Bs[128 * 32];
  const int f = blockIdx.x, tid = threadIdx.x;
  if (f < 128) {
    const int which = f >> 6, blk = f & 63;
    const unsigned short* A  = which ? W4t : W2b;
    const unsigned short* Bt = which ? W3b : W1b;
    unsigned short* C = which ? W34tb : Mtb;
    const int m0 = (blk >> 3) * 128, n0 = (blk & 7) * 128;
    const int wave = tid >> 6, lane = tid & 63;
    f32x4 acc[4][4] = {};
    const int wr = wave >> 1, wc = wave & 1;
    const int fr = lane & 15, fq = lane >> 4;
    const int si0 = wave * 2, sr = lane >> 2, sce = (lane & 3) * 8;
    for (int k0 = 0; k0 < 1024; k0 += 32) {
#pragma unroll
      for (int c = 0; c < 2; ++c) {
        const int i = si0 + c, rr = i * 16 + sr;
        gload_lds16(A  + (size_t)(m0 + rr) * 1024 + k0 + sce, As + i * 512 + lane * 8);
        gload_lds16(Bt + (size_t)(n0 + rr) * 1024 + k0 + sce, Bs + i * 512 + lane * 8);
      }
      __syncthreads();
      bf16x8 af[4], bg[4];
#pragma unroll
      for (int m = 0; m < 4; ++m)
        af[m] = *(const bf16x8*)(As + (wr * 64 + m * 16 + fr) * 32 + fq * 8);
#pragma unroll
      for (int n = 0; n < 4; ++n)
        bg[n] = *(const bf16x8*)(Bs + (wc * 64 + n * 16 + fr) * 32 + fq * 8);
#pragma unroll
      for (int m = 0; m < 4; ++m)
#pragma unroll
        for (int n = 0; n < 4; ++n)
          acc[m][n] = __builtin_amdgcn_mfma_f32_16x16x32_bf16(af[m], bg[n], acc[m][n], 0, 0, 0);
      __syncthreads();
    }
#pragma unroll
    for (int m = 0; m < 4; ++m) {
      const int rbase = m0 + wr * 64 + m * 16 + fq * 4;
#pragma unroll
      for (int j = 0; j < 4; ++j)
#pragma unroll
        for (int n = 0; n < 4; ++n)
          C[(size_t)(rbase + j) * 1024 + (n0 + wc * 64 + n * 16 + fr)] = f2bf(acc[m][n][j]);
    }
  } else if (f < 640) {
    const int f2 = f - 128;
    if (f2 < 4) {
      uint4 z = {0, 0, 0, 0};
      float* p = rsum + f2 * 2048 + tid * 8;
      *(uint4*)p = z; *(uint4*)(p + 4) = z;
    }
    const int wave = tid >> 6, lane = tid & 63;
#pragma unroll 4
    for (int rr = 0; rr < 4; ++rr) {
      const int i = f2 * 16 + wave * 4 + rr;
      const unsigned short* row = xb + (size_t)i * 1024;
      float acc = 0.f;
#pragma unroll 2
      for (int it = 0; it < 2; ++it) {
        const int k0 = (it * 64 + lane) * 8;
        bf16x8 pk = *(const bf16x8*)(row + k0);
#pragma unroll
        for (int j = 0; j < 8; ++j)
          acc += bf2f(((const unsigned short*)&pk)[j]) * w21[k0 + j];
      }
#pragma unroll
      for (int o = 32; o; o >>= 1) acc += __shfl_xor(acc, o);
      if (lane == 0) vvec[i] = acc;
    }
  } else {
    const int e = (f - 640) * 4 + (tid >> 6);
    const int lane = tid & 63;
    float acc = 0.f;
#pragma unroll 4
    for (int i = 0; i < 16; ++i) {
      const int j = i * 64 + lane;
      acc += bf2f(W4t[(size_t)e * 1024 + j]) * b3[j];
    }
#pragma unroll
    for (int o = 32; o; o >>= 1) acc += __shfl_xor(acc, o);
    if (lane == 0) bfv[e] = acc + b4[e];
  }
}

// ---------------------------------------------------------------------------
extern "C" void kernel_launch(void* const* d_in, const int* in_sizes, int n_in,
                              void* d_out, int out_size, void* d_ws, size_t ws_size,
                              hipStream_t stream)
{
  const float* x  = (const float*)d_in[0];
  const float* W1 = (const float*)d_in[1];
  const float* b1 = (const float*)d_in[2];
  const float* W2 = (const float*)d_in[3];
  // b2 unused: cancels in softmax (row-constant terms)
  const float* W3 = (const float*)d_in[5];
  const float* b3 = (const float*)d_in[6];
  const float* W4 = (const float*)d_in[7];
  const float* b4 = (const float*)d_in[8];

  char* ws = (char*)d_ws;
  const size_t MB = 1024 * 1024;
  unsigned short* xb    = (unsigned short*)(ws);            // 16MB
  unsigned short* W4t   = (unsigned short*)(ws + 16 * MB);  // 2MB
  unsigned short* W2b   = (unsigned short*)(ws + 18 * MB);  // 2MB
  unsigned short* W1b   = (unsigned short*)(ws + 20 * MB);  // 2MB
  unsigned short* W3b   = (unsigned short*)(ws + 22 * MB);  // 2MB
  unsigned short* G     = (unsigned short*)(ws + 24 * MB);  // 16MB: x @ M
  unsigned short* Mtb   = (unsigned short*)(ws + 40 * MB);  // 2MB
  unsigned short* W34tb = (unsigned short*)(ws + 42 * MB);  // 2MB
  float*          rsum  = (float*)(ws + 44 * MB);           // 32KB
  float*          bfv   = (float*)(ws + 45 * MB);           // 4KB
  float*          w21   = (float*)(ws + 45 * MB + 8192);    // 4KB
  float*          vvec  = (float*)(ws + 45 * MB + 16384);   // 32KB
  unsigned short* Vt    = (unsigned short*)(ws + 56 * MB);  // 16MB
  unsigned short* S     = (unsigned short*)(ws + 72 * MB);  // 32MB exp values

  // 1. x/W converts, W4 transpose, w21
  bigprep<<<6144, 256, 0, stream>>>(x, W1, W2, W3, W4, b1,
                                    xb, W1b, W2b, W3b, W4t, w21);

  // 2. Mtb/W34tb GEMMs + v-vector + rsum zero + bfv
  prep2<<<896, 256, 0, stream>>>(W2b, W1b, W4t, W3b, Mtb, W34tb,
                                 xb, w21, b3, b4, vvec, rsum, bfv);

  // 3. G = xb @ Mtb^T  [8192][1024]  ||  Vt[z] = W34tb @ xb[z]^T  [4][1024][2048]
  gemm256_dual<<<512, 512, 0, stream>>>(xb, Mtb, G, W34tb, xb, Vt,
                                        0, 2048L * 1024, 1024L * 2048);

  // 4. S[z] = exp((G[z] @ xb[z]^T + v[col]) / 32), rowsum -> rsum
  gemm256<256, 3, false, 1024, 1024, 1024, 2048><<<dim3(8, 8, 4), 512, 0, stream>>>(
      G, xb, vvec, rsum, S, 0.03125f,
      2048L * 1024, 2048L * 1024, 2048L * 2048);

  // 5. out[z] = (S[z] @ V'[z]) * rcp(rsum[row]) + bfv[col]  (fp32)
  gemm256<128, 5, true, 2048, 2048, 2048, 1024><<<dim3(8, 8, 4), 512, 0, stream>>>(
      S, Vt, bfv, rsum, d_out, 1.f,
      2048L * 2048, 1024L * 2048, 2048L * 1024);
}